// Round 4
// baseline (977.884 us; speedup 1.0000x reference)
//
#include <hip/hip_runtime.h>

typedef short short8 __attribute__((ext_vector_type(8)));
typedef float f32x4 __attribute__((ext_vector_type(4)));

#define IN_DIM   33
#define HID      64
#define OUT_DIM  2
#define PRED_LEN 25
#define NB       1024
#define NP       22
#define NT       20
#define EPS      1e-5f

// swizzled element index into a [32][128] bf16 LDS tile (row stride 256B):
// XOR k with (s&7)<<3 spreads stride-256B columns across banks, keeps
// 8-element (16B) alignment for ds_read_b128.
#define SWZ(s,k) (((s) << 7) + ((k) ^ (((s) & 7) << 3)))

__device__ __forceinline__ float fast_rcp(float x){ return __builtin_amdgcn_rcpf(x); }
__device__ __forceinline__ float sigm(float x){ return fast_rcp(1.0f + __expf(-x)); }
__device__ __forceinline__ float tanhf_(float x){ float e = __expf(2.0f*x); return 1.0f - 2.0f*fast_rcp(e + 1.0f); }
// round-to-nearest-even f32 -> bf16 (scalar path, used in setup/staging)
__device__ __forceinline__ unsigned short bf_hi(float f){
    unsigned u = __float_as_uint(f);
    return (unsigned short)((u + 0x7fffu + ((u >> 16) & 1u)) >> 16);
}
__device__ __forceinline__ float bf_f(unsigned short h){ return __uint_as_float(((unsigned)h) << 16); }
// packed f32x2 -> bf16x2 (lo16 = bf16(a), hi16 = bf16(b)), RTNE
__device__ __forceinline__ unsigned cvt_pk_bf16(float a, float b){
    unsigned r;
    asm("v_cvt_pk_bf16_f32 %0, %1, %2" : "=v"(r) : "v"(a), "v"(b));
    return r;
}

__global__ __launch_bounds__(256, 4) void nfl_mfma(
    const float* __restrict__ x,
    const float* __restrict__ enc_Wih, const float* __restrict__ enc_Whh,
    const float* __restrict__ enc_bih, const float* __restrict__ enc_bhh,
    const float* __restrict__ q_W, const float* __restrict__ q_b,
    const float* __restrict__ k_W, const float* __restrict__ k_b,
    const float* __restrict__ v_W, const float* __restrict__ v_b,
    const float* __restrict__ ln_g, const float* __restrict__ ln_b,
    const float* __restrict__ dec_Wih, const float* __restrict__ dec_Whh,
    const float* __restrict__ dec_bih, const float* __restrict__ dec_bhh,
    const float* __restrict__ fc_W, const float* __restrict__ fc_b,
    float* __restrict__ out)
{
    // A-tile arena: [32][128] u16 hi + [32][128] u16 lo = 16 KB.
    // During the attention phase (A dead between QKV-MFMA and LN write-back)
    // the same bytes hold K (first half) and V (second half) as fp32 [22][66].
    __shared__ __align__(16) unsigned char arena[32*128*2*2];
    __shared__ float sh_q [NP*66];
    __shared__ float sh_f [NP*66];
    __shared__ float sh_sc[NP*24];
    __shared__ float sh_p0[32];
    __shared__ float sh_p1[32];
    __shared__ float sh_mu[NP];
    __shared__ float sh_rs[NP];

    unsigned short* shA_hi = (unsigned short*)arena;           // 32*128
    unsigned short* shA_lo = (unsigned short*)(arena + 8192);  // 32*128
    float* sh_k = (float*)arena;            // alias, attention phase only
    float* sh_v = (float*)(arena + 8192);   // alias, attention phase only

    const int tid  = threadIdx.x;
    const int w    = tid >> 6;        // wave id 0..3
    const int ln   = tid & 63;
    const int lo15 = ln & 15;
    const int qq   = ln >> 4;         // lane quarter 0..3
    const int jh   = 16*w + lo15;     // this lane's hidden column (0..63)
    const int b    = blockIdx.x;
    const float* xb = x + (size_t)b * NP*NT*IN_DIM;

    // ---- encoder B fragments in registers (split bf16) ----
    // B[k][g] = enc_Whh[g][k] (k<64) | enc_Wih[g][k-64] (k-64<33) | 0
    short8 eBh[4][4], eBl[4][4];
    float bias_e[4];
    #pragma unroll
    for (int nt = 0; nt < 4; nt++){
        int g = 16*w + 64*nt + lo15;
        bias_e[nt] = enc_bih[g] + enc_bhh[g];
        #pragma unroll
        for (int kt = 0; kt < 4; kt++){
            #pragma unroll
            for (int e = 0; e < 8; e++){
                int k = 32*kt + 8*qq + e;
                float v;
                if (k < HID) v = enc_Whh[g*HID + k];
                else { int d = k - HID; v = (d < IN_DIM) ? enc_Wih[g*IN_DIM + d] : 0.0f; }
                unsigned short h = bf_hi(v);
                eBh[nt][kt][e] = (short)h;
                eBl[nt][kt][e] = (short)bf_hi(v - bf_f(h));
            }
        }
    }

    // zero A tile (padded rows 22..31 and cols 97..127 must stay zero)
    for (int i = tid; i < 32*128; i += 256) ((unsigned*)arena)[i] = 0;  // 16KB as u32

    float cst[2][4] = {{0,0,0,0},{0,0,0,0}};   // cell state, per-lane
    __syncthreads();

    // x_t staging into A cols 64..96 (split bf16, swizzled)
    auto stage_x = [&](int t){
        for (int i = tid; i < NP*IN_DIM; i += 256){
            int s = i / IN_DIM, d = i - s * IN_DIM;
            float v = xb[(s*NT + t)*IN_DIM + d];
            unsigned short h = bf_hi(v);
            int idx = SWZ(s, HID + d);
            shA_hi[idx] = h; shA_lo[idx] = bf_hi(v - bf_f(h));
        }
    };

    // LSTM nonlinearity from in-register gates; h -> split bf16 into A tile
    auto nonlin_store = [&](f32x4 (&acc)[2][4], bool save_f){
        #pragma unroll
        for (int m = 0; m < 2; m++){
            #pragma unroll
            for (int jp = 0; jp < 2; jp++){
                const int j0 = 2*jp;
                float hh0, hh1;
                {
                    float gi=acc[m][0][j0], gf=acc[m][1][j0], gg=acc[m][2][j0], go=acc[m][3][j0];
                    float c = sigm(gf)*cst[m][j0] + sigm(gi)*tanhf_(gg);
                    cst[m][j0] = c;
                    hh0 = sigm(go)*tanhf_(c);
                }
                {
                    float gi=acc[m][0][j0+1], gf=acc[m][1][j0+1], gg=acc[m][2][j0+1], go=acc[m][3][j0+1];
                    float c = sigm(gf)*cst[m][j0+1] + sigm(gi)*tanhf_(gg);
                    cst[m][j0+1] = c;
                    hh1 = sigm(go)*tanhf_(c);
                }
                unsigned hp = cvt_pk_bf16(hh0, hh1);
                float r0 = hh0 - __uint_as_float(hp << 16);
                float r1 = hh1 - __uint_as_float(hp & 0xffff0000u);
                unsigned lp = cvt_pk_bf16(r0, r1);
                const int s0 = 16*m + 4*qq + j0;
                if (s0 < NP){
                    int i0 = SWZ(s0, jh);
                    shA_hi[i0] = (unsigned short)hp;
                    shA_lo[i0] = (unsigned short)lp;
                    if (save_f) sh_f[s0*66 + jh] = hh0;
                }
                if (s0 + 1 < NP){
                    int i1 = SWZ(s0 + 1, jh);
                    shA_hi[i1] = (unsigned short)(hp >> 16);
                    shA_lo[i1] = (unsigned short)(lp >> 16);
                    if (save_f) sh_f[(s0+1)*66 + jh] = hh1;
                }
            }
        }
    };

    // =================== encoder: 20 MFMA LSTM steps ===================
    stage_x(0);
    __syncthreads();
    for (int t = 0; t < NT; t++){
        f32x4 acc[2][4];
        #pragma unroll
        for (int m = 0; m < 2; m++)
            #pragma unroll
            for (int nt = 0; nt < 4; nt++){
                float bb = bias_e[nt];
                acc[m][nt][0]=bb; acc[m][nt][1]=bb; acc[m][nt][2]=bb; acc[m][nt][3]=bb;
            }
        #pragma unroll
        for (int kt = 0; kt < 4; kt++){
            #pragma unroll
            for (int m = 0; m < 2; m++){
                int idx = SWZ(16*m + lo15, 32*kt + 8*qq);
                short8 ah = *reinterpret_cast<const short8*>(&shA_hi[idx]);
                short8 al = *reinterpret_cast<const short8*>(&shA_lo[idx]);
                #pragma unroll
                for (int nt = 0; nt < 4; nt++){
                    acc[m][nt] = __builtin_amdgcn_mfma_f32_16x16x32_bf16(ah, eBh[nt][kt], acc[m][nt], 0,0,0);
                    acc[m][nt] = __builtin_amdgcn_mfma_f32_16x16x32_bf16(al, eBh[nt][kt], acc[m][nt], 0,0,0);
                    acc[m][nt] = __builtin_amdgcn_mfma_f32_16x16x32_bf16(ah, eBl[nt][kt], acc[m][nt], 0,0,0);
                }
            }
        }
        __syncthreads();                 // all A reads done
        if (t + 1 < NT) stage_x(t + 1);  // disjoint cols vs h writes
        nonlin_store(acc, t == NT-1);
        __syncthreads();                 // h (and x_{t+1}) visible
    }

    // =================== attention: QKV via MFMA ===================
    {
        short8 qBh[3][2], qBl[3][2];
        float qb3[3];
        #pragma unroll
        for (int mat = 0; mat < 3; mat++){
            const float* W  = (mat==0) ? q_W : (mat==1) ? k_W : v_W;
            const float* bb = (mat==0) ? q_b : (mat==1) ? k_b : v_b;
            qb3[mat] = bb[jh];
            #pragma unroll
            for (int kt = 0; kt < 2; kt++){
                #pragma unroll
                for (int e = 0; e < 8; e++){
                    int k = 32*kt + 8*qq + e;
                    float v = W[jh*HID + k];
                    unsigned short h = bf_hi(v);
                    qBh[mat][kt][e] = (short)h;
                    qBl[mat][kt][e] = (short)bf_hi(v - bf_f(h));
                }
            }
        }
        f32x4 qacc[3][2];
        #pragma unroll
        for (int mat = 0; mat < 3; mat++)
            #pragma unroll
            for (int m = 0; m < 2; m++){
                float bb = qb3[mat];
                qacc[mat][m][0]=bb; qacc[mat][m][1]=bb; qacc[mat][m][2]=bb; qacc[mat][m][3]=bb;
            }
        #pragma unroll
        for (int kt = 0; kt < 2; kt++){
            #pragma unroll
            for (int m = 0; m < 2; m++){
                int idx = SWZ(16*m + lo15, 32*kt + 8*qq);
                short8 ah = *reinterpret_cast<const short8*>(&shA_hi[idx]);
                short8 al = *reinterpret_cast<const short8*>(&shA_lo[idx]);
                #pragma unroll
                for (int mat = 0; mat < 3; mat++){
                    qacc[mat][m] = __builtin_amdgcn_mfma_f32_16x16x32_bf16(ah, qBh[mat][kt], qacc[mat][m], 0,0,0);
                    qacc[mat][m] = __builtin_amdgcn_mfma_f32_16x16x32_bf16(al, qBh[mat][kt], qacc[mat][m], 0,0,0);
                    qacc[mat][m] = __builtin_amdgcn_mfma_f32_16x16x32_bf16(ah, qBl[mat][kt], qacc[mat][m], 0,0,0);
                }
            }
        }
        __syncthreads();   // A reads done before K/V overwrite the arena
        #pragma unroll
        for (int mat = 0; mat < 3; mat++){
            float* dst = (mat==0) ? sh_q : (mat==1) ? sh_k : sh_v;
            #pragma unroll
            for (int m = 0; m < 2; m++)
                #pragma unroll
                for (int j = 0; j < 4; j++){
                    int s = 16*m + 4*qq + j;
                    if (s < NP) dst[s*66 + jh] = qacc[mat][m][j];
                }
        }
    }
    __syncthreads();

    // scores = QK^T / 8
    for (int i = tid; i < NP*NP; i += 256){
        int p = i / NP, q = i - p*NP;
        float acc = 0.0f;
        #pragma unroll
        for (int k = 0; k < HID; k++) acc = fmaf(sh_q[p*66 + k], sh_k[q*66 + k], acc);
        sh_sc[p*24 + q] = acc * 0.125f;
    }
    __syncthreads();

    if (tid < NP){
        float m = -1e30f;
        for (int q = 0; q < NP; q++) m = fmaxf(m, sh_sc[tid*24 + q]);
        float sum = 0.0f;
        for (int q = 0; q < NP; q++){ float e = __expf(sh_sc[tid*24 + q] - m); sh_sc[tid*24 + q] = e; sum += e; }
        float inv = fast_rcp(sum);
        for (int q = 0; q < NP; q++) sh_sc[tid*24 + q] *= inv;
    }
    __syncthreads();

    // y = h + attn@V  (in place into sh_f)
    for (int i = tid; i < NP*HID; i += 256){
        int s = i >> 6, j = i & 63;
        float acc = 0.0f;
        #pragma unroll
        for (int q = 0; q < NP; q++) acc = fmaf(sh_sc[s*24 + q], sh_v[q*66 + j], acc);
        sh_f[s*66 + j] += acc;
    }
    __syncthreads();

    // layernorm stats
    if (tid < NP){
        float mu = 0.0f;
        for (int j = 0; j < HID; j++) mu += sh_f[tid*66 + j];
        mu *= (1.0f/HID);
        float var = 0.0f;
        for (int j = 0; j < HID; j++){ float d = sh_f[tid*66 + j] - mu; var += d*d; }
        sh_mu[tid] = mu;
        sh_rs[tid] = rsqrtf(var*(1.0f/HID) + EPS);
    }
    __syncthreads();

    // LN apply -> decoder h0 into A tile (split bf16, packed u32 stores).
    // Rows 22..31 / cols>=64 of A now hold K/V garbage; decoder only consumes
    // rows<22 (guards discard D rows >=22) and cols<64 (K=64), so that's fine.
    for (int i = tid; i < NP*HID/2; i += 256){
        int s = i >> 5, j0 = (i & 31) << 1;
        float sc = sh_rs[s], mu = sh_mu[s];
        float v0 = (sh_f[s*66 + j0]   - mu) * sc * ln_g[j0]   + ln_b[j0];
        float v1 = (sh_f[s*66 + j0+1] - mu) * sc * ln_g[j0+1] + ln_b[j0+1];
        unsigned hp = cvt_pk_bf16(v0, v1);
        float r0 = v0 - __uint_as_float(hp << 16);
        float r1 = v1 - __uint_as_float(hp & 0xffff0000u);
        unsigned lp = cvt_pk_bf16(r0, r1);
        int idx = SWZ(s, j0);   // j0 even -> idx even -> 4B aligned
        *(unsigned*)&shA_hi[idx] = hp;
        *(unsigned*)&shA_lo[idx] = lp;
    }
    if (tid < 32){
        float v0 = 0.0f, v1 = 0.0f;
        if (tid < NP){
            v0 = xb[(tid*NT + NT-1)*IN_DIM + 0];
            v1 = xb[(tid*NT + NT-1)*IN_DIM + 1];
        }
        sh_p0[tid] = v0; sh_p1[tid] = v1;
    }

    // ---- decoder B fragments + FC weights ----
    short8 dBh[4][2], dBl[4][2];
    float bias_d[4], wd0[4], wd1[4];
    #pragma unroll
    for (int nt = 0; nt < 4; nt++){
        int g = 16*w + 64*nt + lo15;
        bias_d[nt] = dec_bih[g] + dec_bhh[g];
        wd0[nt] = dec_Wih[g*OUT_DIM + 0];
        wd1[nt] = dec_Wih[g*OUT_DIM + 1];
        #pragma unroll
        for (int kt = 0; kt < 2; kt++){
            #pragma unroll
            for (int e = 0; e < 8; e++){
                int k = 32*kt + 8*qq + e;
                float v = dec_Whh[g*HID + k];
                unsigned short h = bf_hi(v);
                dBh[nt][kt][e] = (short)h;
                dBl[nt][kt][e] = (short)bf_hi(v - bf_f(h));
            }
        }
    }
    const int fitem = tid >> 2, fq = tid & 3, fs = fitem >> 1, fo = fitem & 1;
    float fcw[16]; float fcb = 0.0f;
    if (tid < 176){
        #pragma unroll
        for (int jj = 0; jj < 16; jj++) fcw[jj] = fc_W[fo*HID + 16*fq + jj];
        fcb = fc_b[fo];
    }
    float* outb = out + (size_t)b * NP * PRED_LEN * OUT_DIM;
    __syncthreads();

    // =================== decoder: 25 MFMA LSTM steps + FC ===================
    for (int t = 0; t < PRED_LEN; t++){
        f32x4 acc[2][4];
        #pragma unroll
        for (int m = 0; m < 2; m++){
            #pragma unroll
            for (int j = 0; j < 4; j++){
                int s = 16*m + 4*qq + j;
                float p0 = sh_p0[s], p1 = sh_p1[s];
                #pragma unroll
                for (int nt = 0; nt < 4; nt++)
                    acc[m][nt][j] = bias_d[nt] + wd0[nt]*p0 + wd1[nt]*p1;
            }
        }
        #pragma unroll
        for (int kt = 0; kt < 2; kt++){
            #pragma unroll
            for (int m = 0; m < 2; m++){
                int idx = SWZ(16*m + lo15, 32*kt + 8*qq);
                short8 ah = *reinterpret_cast<const short8*>(&shA_hi[idx]);
                short8 al = *reinterpret_cast<const short8*>(&shA_lo[idx]);
                #pragma unroll
                for (int nt = 0; nt < 4; nt++){
                    acc[m][nt] = __builtin_amdgcn_mfma_f32_16x16x32_bf16(ah, dBh[nt][kt], acc[m][nt], 0,0,0);
                    acc[m][nt] = __builtin_amdgcn_mfma_f32_16x16x32_bf16(al, dBh[nt][kt], acc[m][nt], 0,0,0);
                    acc[m][nt] = __builtin_amdgcn_mfma_f32_16x16x32_bf16(ah, dBl[nt][kt], acc[m][nt], 0,0,0);
                }
            }
        }
        __syncthreads();   // A/p reads done before overwrite

        nonlin_store(acc, false);
        __syncthreads();   // h visible for FC

        if (tid < 176){
            int idx0 = SWZ(fs, 16*fq);
            int idx1 = SWZ(fs, 16*fq + 8);
            short8 h0h = *reinterpret_cast<const short8*>(&shA_hi[idx0]);
            short8 h0l = *reinterpret_cast<const short8*>(&shA_lo[idx0]);
            short8 h1h = *reinterpret_cast<const short8*>(&shA_hi[idx1]);
            short8 h1l = *reinterpret_cast<const short8*>(&shA_lo[idx1]);
            float part = 0.0f;
            #pragma unroll
            for (int e = 0; e < 8; e++){
                part = fmaf(bf_f((unsigned short)h0h[e]) + bf_f((unsigned short)h0l[e]), fcw[e],     part);
                part = fmaf(bf_f((unsigned short)h1h[e]) + bf_f((unsigned short)h1l[e]), fcw[8 + e], part);
            }
            part += __shfl_xor(part, 1);
            part += __shfl_xor(part, 2);
            if (fq == 0){
                float pred = part + fcb;
                outb[(fs*PRED_LEN + t)*OUT_DIM + fo] = pred;
                if (fo == 0) sh_p0[fs] = pred; else sh_p1[fs] = pred;
            }
        }
        __syncthreads();   // sh_p ready for next step
    }
}

extern "C" void kernel_launch(void* const* d_in, const int* in_sizes, int n_in,
                              void* d_out, int out_size, void* d_ws, size_t ws_size,
                              hipStream_t stream) {
    const float* x        = (const float*)d_in[0];
    const float* enc_Wih  = (const float*)d_in[1];
    const float* enc_Whh  = (const float*)d_in[2];
    const float* enc_bih  = (const float*)d_in[3];
    const float* enc_bhh  = (const float*)d_in[4];
    const float* q_W      = (const float*)d_in[5];
    const float* q_b      = (const float*)d_in[6];
    const float* k_W      = (const float*)d_in[7];
    const float* k_b      = (const float*)d_in[8];
    const float* v_W      = (const float*)d_in[9];
    const float* v_b      = (const float*)d_in[10];
    const float* ln_g     = (const float*)d_in[11];
    const float* ln_b     = (const float*)d_in[12];
    const float* dec_Wih  = (const float*)d_in[13];
    const float* dec_Whh  = (const float*)d_in[14];
    const float* dec_bih  = (const float*)d_in[15];
    const float* dec_bhh  = (const float*)d_in[16];
    const float* fc_W     = (const float*)d_in[17];
    const float* fc_b     = (const float*)d_in[18];
    float* out = (float*)d_out;

    nfl_mfma<<<dim3(NB), dim3(256), 0, stream>>>(
        x, enc_Wih, enc_Whh, enc_bih, enc_bhh,
        q_W, q_b, k_W, k_b, v_W, v_b, ln_g, ln_b,
        dec_Wih, dec_Whh, dec_bih, dec_bhh, fc_W, fc_b, out);
}

// Round 5
// 385.084 us; speedup vs baseline: 2.5394x; 2.5394x over previous
//
#include <hip/hip_runtime.h>

typedef short short8 __attribute__((ext_vector_type(8)));
typedef float f32x4 __attribute__((ext_vector_type(4)));

#define IN_DIM   33
#define HID      64
#define OUT_DIM  2
#define PRED_LEN 25
#define NB       1024
#define NP       22
#define NT       20
#define EPS      1e-5f

// swizzled element index into a [32][128] bf16 LDS tile (row stride 256B):
// XOR k with (s&7)<<3 spreads stride-256B columns across banks, keeps
// 8-element (16B) alignment for ds_read_b128.
#define SWZ(s,k) (((s) << 7) + ((k) ^ (((s) & 7) << 3)))

__device__ __forceinline__ float fast_rcp(float x){ return __builtin_amdgcn_rcpf(x); }
__device__ __forceinline__ float sigm(float x){ return fast_rcp(1.0f + __expf(-x)); }
__device__ __forceinline__ float tanhf_(float x){ float e = __expf(2.0f*x); return 1.0f - 2.0f*fast_rcp(e + 1.0f); }
// round-to-nearest-even f32 -> bf16 (scalar path, used in setup/staging)
__device__ __forceinline__ unsigned short bf_hi(float f){
    unsigned u = __float_as_uint(f);
    return (unsigned short)((u + 0x7fffu + ((u >> 16) & 1u)) >> 16);
}
__device__ __forceinline__ float bf_f(unsigned short h){ return __uint_as_float(((unsigned)h) << 16); }
// packed f32x2 -> bf16x2 (lo16 = bf16(a), hi16 = bf16(b)), RTNE
__device__ __forceinline__ unsigned cvt_pk_bf16(float a, float b){
    unsigned r;
    asm("v_cvt_pk_bf16_f32 %0, %1, %2" : "=v"(r) : "v"(a), "v"(b));
    return r;
}

// NOTE launch bounds: kernel keeps ~128 VGPRs of B-fragments live (encoder
// phase floor). (256,4) forced a 64-VGPR cap -> catastrophic scratch spill
// (R4: FETCH 2.4 GB/dispatch). (256,2) gives VGPR=128 with zero spill; at
// 128 VGPR the HW still allows 4 waves/SIMD -> 4 blocks/CU since LDS is
// only 30.7 KB. Do not raise the min-waves demand again.
__global__ __launch_bounds__(256, 2) void nfl_mfma(
    const float* __restrict__ x,
    const float* __restrict__ enc_Wih, const float* __restrict__ enc_Whh,
    const float* __restrict__ enc_bih, const float* __restrict__ enc_bhh,
    const float* __restrict__ q_W, const float* __restrict__ q_b,
    const float* __restrict__ k_W, const float* __restrict__ k_b,
    const float* __restrict__ v_W, const float* __restrict__ v_b,
    const float* __restrict__ ln_g, const float* __restrict__ ln_b,
    const float* __restrict__ dec_Wih, const float* __restrict__ dec_Whh,
    const float* __restrict__ dec_bih, const float* __restrict__ dec_bhh,
    const float* __restrict__ fc_W, const float* __restrict__ fc_b,
    float* __restrict__ out)
{
    // A-tile arena: [32][128] u16 hi + [32][128] u16 lo = 16 KB.
    // During the attention phase (A dead between QKV-MFMA and LN write-back)
    // the same bytes hold K (first half) and V (second half) as fp32 [22][66].
    __shared__ __align__(16) unsigned char arena[32*128*2*2];
    __shared__ float sh_q [NP*66];
    __shared__ float sh_f [NP*66];
    __shared__ float sh_sc[NP*24];
    __shared__ float sh_p0[32];
    __shared__ float sh_p1[32];
    __shared__ float sh_mu[NP];
    __shared__ float sh_rs[NP];

    unsigned short* shA_hi = (unsigned short*)arena;           // 32*128
    unsigned short* shA_lo = (unsigned short*)(arena + 8192);  // 32*128
    float* sh_k = (float*)arena;            // alias, attention phase only
    float* sh_v = (float*)(arena + 8192);   // alias, attention phase only

    const int tid  = threadIdx.x;
    const int w    = tid >> 6;        // wave id 0..3
    const int ln   = tid & 63;
    const int lo15 = ln & 15;
    const int qq   = ln >> 4;         // lane quarter 0..3
    const int jh   = 16*w + lo15;     // this lane's hidden column (0..63)
    const int b    = blockIdx.x;
    const float* xb = x + (size_t)b * NP*NT*IN_DIM;

    // ---- encoder B fragments in registers (split bf16) ----
    // B[k][g] = enc_Whh[g][k] (k<64) | enc_Wih[g][k-64] (k-64<33) | 0
    short8 eBh[4][4], eBl[4][4];
    float bias_e[4];
    #pragma unroll
    for (int nt = 0; nt < 4; nt++){
        int g = 16*w + 64*nt + lo15;
        bias_e[nt] = enc_bih[g] + enc_bhh[g];
        #pragma unroll
        for (int kt = 0; kt < 4; kt++){
            #pragma unroll
            for (int e = 0; e < 8; e++){
                int k = 32*kt + 8*qq + e;
                float v;
                if (k < HID) v = enc_Whh[g*HID + k];
                else { int d = k - HID; v = (d < IN_DIM) ? enc_Wih[g*IN_DIM + d] : 0.0f; }
                unsigned short h = bf_hi(v);
                eBh[nt][kt][e] = (short)h;
                eBl[nt][kt][e] = (short)bf_hi(v - bf_f(h));
            }
        }
    }

    // zero A tile (padded rows 22..31 and cols 97..127 must stay zero)
    for (int i = tid; i < 32*128; i += 256) ((unsigned*)arena)[i] = 0;  // 16KB as u32

    float cst[2][4] = {{0,0,0,0},{0,0,0,0}};   // cell state, per-lane
    __syncthreads();

    // x_t staging into A cols 64..96 (split bf16, swizzled)
    auto stage_x = [&](int t){
        for (int i = tid; i < NP*IN_DIM; i += 256){
            int s = i / IN_DIM, d = i - s * IN_DIM;
            float v = xb[(s*NT + t)*IN_DIM + d];
            unsigned short h = bf_hi(v);
            int idx = SWZ(s, HID + d);
            shA_hi[idx] = h; shA_lo[idx] = bf_hi(v - bf_f(h));
        }
    };

    // LSTM nonlinearity from in-register gates; h -> split bf16 into A tile
    auto nonlin_store = [&](f32x4 (&acc)[2][4], bool save_f){
        #pragma unroll
        for (int m = 0; m < 2; m++){
            #pragma unroll
            for (int jp = 0; jp < 2; jp++){
                const int j0 = 2*jp;
                float hh0, hh1;
                {
                    float gi=acc[m][0][j0], gf=acc[m][1][j0], gg=acc[m][2][j0], go=acc[m][3][j0];
                    float c = sigm(gf)*cst[m][j0] + sigm(gi)*tanhf_(gg);
                    cst[m][j0] = c;
                    hh0 = sigm(go)*tanhf_(c);
                }
                {
                    float gi=acc[m][0][j0+1], gf=acc[m][1][j0+1], gg=acc[m][2][j0+1], go=acc[m][3][j0+1];
                    float c = sigm(gf)*cst[m][j0+1] + sigm(gi)*tanhf_(gg);
                    cst[m][j0+1] = c;
                    hh1 = sigm(go)*tanhf_(c);
                }
                unsigned hp = cvt_pk_bf16(hh0, hh1);
                float r0 = hh0 - __uint_as_float(hp << 16);
                float r1 = hh1 - __uint_as_float(hp & 0xffff0000u);
                unsigned lp = cvt_pk_bf16(r0, r1);
                const int s0 = 16*m + 4*qq + j0;
                if (s0 < NP){
                    int i0 = SWZ(s0, jh);
                    shA_hi[i0] = (unsigned short)hp;
                    shA_lo[i0] = (unsigned short)lp;
                    if (save_f) sh_f[s0*66 + jh] = hh0;
                }
                if (s0 + 1 < NP){
                    int i1 = SWZ(s0 + 1, jh);
                    shA_hi[i1] = (unsigned short)(hp >> 16);
                    shA_lo[i1] = (unsigned short)(lp >> 16);
                    if (save_f) sh_f[(s0+1)*66 + jh] = hh1;
                }
            }
        }
    };

    // =================== encoder: 20 MFMA LSTM steps ===================
    stage_x(0);
    __syncthreads();
    for (int t = 0; t < NT; t++){
        f32x4 acc[2][4];
        #pragma unroll
        for (int m = 0; m < 2; m++)
            #pragma unroll
            for (int nt = 0; nt < 4; nt++){
                float bb = bias_e[nt];
                acc[m][nt][0]=bb; acc[m][nt][1]=bb; acc[m][nt][2]=bb; acc[m][nt][3]=bb;
            }
        #pragma unroll
        for (int kt = 0; kt < 4; kt++){
            #pragma unroll
            for (int m = 0; m < 2; m++){
                int idx = SWZ(16*m + lo15, 32*kt + 8*qq);
                short8 ah = *reinterpret_cast<const short8*>(&shA_hi[idx]);
                short8 al = *reinterpret_cast<const short8*>(&shA_lo[idx]);
                #pragma unroll
                for (int nt = 0; nt < 4; nt++){
                    acc[m][nt] = __builtin_amdgcn_mfma_f32_16x16x32_bf16(ah, eBh[nt][kt], acc[m][nt], 0,0,0);
                    acc[m][nt] = __builtin_amdgcn_mfma_f32_16x16x32_bf16(al, eBh[nt][kt], acc[m][nt], 0,0,0);
                    acc[m][nt] = __builtin_amdgcn_mfma_f32_16x16x32_bf16(ah, eBl[nt][kt], acc[m][nt], 0,0,0);
                }
            }
        }
        __syncthreads();                 // all A reads done
        if (t + 1 < NT) stage_x(t + 1);  // disjoint cols vs h writes
        nonlin_store(acc, t == NT-1);
        __syncthreads();                 // h (and x_{t+1}) visible
    }

    // =================== attention: QKV via MFMA ===================
    {
        short8 qBh[3][2], qBl[3][2];
        float qb3[3];
        #pragma unroll
        for (int mat = 0; mat < 3; mat++){
            const float* W  = (mat==0) ? q_W : (mat==1) ? k_W : v_W;
            const float* bb = (mat==0) ? q_b : (mat==1) ? k_b : v_b;
            qb3[mat] = bb[jh];
            #pragma unroll
            for (int kt = 0; kt < 2; kt++){
                #pragma unroll
                for (int e = 0; e < 8; e++){
                    int k = 32*kt + 8*qq + e;
                    float v = W[jh*HID + k];
                    unsigned short h = bf_hi(v);
                    qBh[mat][kt][e] = (short)h;
                    qBl[mat][kt][e] = (short)bf_hi(v - bf_f(h));
                }
            }
        }
        f32x4 qacc[3][2];
        #pragma unroll
        for (int mat = 0; mat < 3; mat++)
            #pragma unroll
            for (int m = 0; m < 2; m++){
                float bb = qb3[mat];
                qacc[mat][m][0]=bb; qacc[mat][m][1]=bb; qacc[mat][m][2]=bb; qacc[mat][m][3]=bb;
            }
        #pragma unroll
        for (int kt = 0; kt < 2; kt++){
            #pragma unroll
            for (int m = 0; m < 2; m++){
                int idx = SWZ(16*m + lo15, 32*kt + 8*qq);
                short8 ah = *reinterpret_cast<const short8*>(&shA_hi[idx]);
                short8 al = *reinterpret_cast<const short8*>(&shA_lo[idx]);
                #pragma unroll
                for (int mat = 0; mat < 3; mat++){
                    qacc[mat][m] = __builtin_amdgcn_mfma_f32_16x16x32_bf16(ah, qBh[mat][kt], qacc[mat][m], 0,0,0);
                    qacc[mat][m] = __builtin_amdgcn_mfma_f32_16x16x32_bf16(al, qBh[mat][kt], qacc[mat][m], 0,0,0);
                    qacc[mat][m] = __builtin_amdgcn_mfma_f32_16x16x32_bf16(ah, qBl[mat][kt], qacc[mat][m], 0,0,0);
                }
            }
        }
        __syncthreads();   // A reads done before K/V overwrite the arena
        #pragma unroll
        for (int mat = 0; mat < 3; mat++){
            float* dst = (mat==0) ? sh_q : (mat==1) ? sh_k : sh_v;
            #pragma unroll
            for (int m = 0; m < 2; m++)
                #pragma unroll
                for (int j = 0; j < 4; j++){
                    int s = 16*m + 4*qq + j;
                    if (s < NP) dst[s*66 + jh] = qacc[mat][m][j];
                }
        }
    }
    __syncthreads();

    // scores = QK^T / 8
    for (int i = tid; i < NP*NP; i += 256){
        int p = i / NP, q = i - p*NP;
        float acc = 0.0f;
        #pragma unroll
        for (int k = 0; k < HID; k++) acc = fmaf(sh_q[p*66 + k], sh_k[q*66 + k], acc);
        sh_sc[p*24 + q] = acc * 0.125f;
    }
    __syncthreads();

    if (tid < NP){
        float m = -1e30f;
        for (int q = 0; q < NP; q++) m = fmaxf(m, sh_sc[tid*24 + q]);
        float sum = 0.0f;
        for (int q = 0; q < NP; q++){ float e = __expf(sh_sc[tid*24 + q] - m); sh_sc[tid*24 + q] = e; sum += e; }
        float inv = fast_rcp(sum);
        for (int q = 0; q < NP; q++) sh_sc[tid*24 + q] *= inv;
    }
    __syncthreads();

    // y = h + attn@V  (in place into sh_f)
    for (int i = tid; i < NP*HID; i += 256){
        int s = i >> 6, j = i & 63;
        float acc = 0.0f;
        #pragma unroll
        for (int q = 0; q < NP; q++) acc = fmaf(sh_sc[s*24 + q], sh_v[q*66 + j], acc);
        sh_f[s*66 + j] += acc;
    }
    __syncthreads();

    // layernorm stats
    if (tid < NP){
        float mu = 0.0f;
        for (int j = 0; j < HID; j++) mu += sh_f[tid*66 + j];
        mu *= (1.0f/HID);
        float var = 0.0f;
        for (int j = 0; j < HID; j++){ float d = sh_f[tid*66 + j] - mu; var += d*d; }
        sh_mu[tid] = mu;
        sh_rs[tid] = rsqrtf(var*(1.0f/HID) + EPS);
    }
    __syncthreads();

    // LN apply -> decoder h0 into A tile (split bf16, packed u32 stores).
    // Rows 22..31 / cols>=64 of A now hold K/V garbage; decoder only consumes
    // rows<22 (guards discard D rows >=22) and cols<64 (K=64), so that's fine.
    for (int i = tid; i < NP*HID/2; i += 256){
        int s = i >> 5, j0 = (i & 31) << 1;
        float sc = sh_rs[s], mu = sh_mu[s];
        float v0 = (sh_f[s*66 + j0]   - mu) * sc * ln_g[j0]   + ln_b[j0];
        float v1 = (sh_f[s*66 + j0+1] - mu) * sc * ln_g[j0+1] + ln_b[j0+1];
        unsigned hp = cvt_pk_bf16(v0, v1);
        float r0 = v0 - __uint_as_float(hp << 16);
        float r1 = v1 - __uint_as_float(hp & 0xffff0000u);
        unsigned lp = cvt_pk_bf16(r0, r1);
        int idx = SWZ(s, j0);   // j0 even -> idx even -> 4B aligned
        *(unsigned*)&shA_hi[idx] = hp;
        *(unsigned*)&shA_lo[idx] = lp;
    }
    if (tid < 32){
        float v0 = 0.0f, v1 = 0.0f;
        if (tid < NP){
            v0 = xb[(tid*NT + NT-1)*IN_DIM + 0];
            v1 = xb[(tid*NT + NT-1)*IN_DIM + 1];
        }
        sh_p0[tid] = v0; sh_p1[tid] = v1;
    }

    // ---- decoder B fragments + FC weights ----
    short8 dBh[4][2], dBl[4][2];
    float bias_d[4], wd0[4], wd1[4];
    #pragma unroll
    for (int nt = 0; nt < 4; nt++){
        int g = 16*w + 64*nt + lo15;
        bias_d[nt] = dec_bih[g] + dec_bhh[g];
        wd0[nt] = dec_Wih[g*OUT_DIM + 0];
        wd1[nt] = dec_Wih[g*OUT_DIM + 1];
        #pragma unroll
        for (int kt = 0; kt < 2; kt++){
            #pragma unroll
            for (int e = 0; e < 8; e++){
                int k = 32*kt + 8*qq + e;
                float v = dec_Whh[g*HID + k];
                unsigned short h = bf_hi(v);
                dBh[nt][kt][e] = (short)h;
                dBl[nt][kt][e] = (short)bf_hi(v - bf_f(h));
            }
        }
    }
    const int fitem = tid >> 2, fq = tid & 3, fs = fitem >> 1, fo = fitem & 1;
    float fcw[16]; float fcb = 0.0f;
    if (tid < 176){
        #pragma unroll
        for (int jj = 0; jj < 16; jj++) fcw[jj] = fc_W[fo*HID + 16*fq + jj];
        fcb = fc_b[fo];
    }
    float* outb = out + (size_t)b * NP * PRED_LEN * OUT_DIM;
    __syncthreads();

    // =================== decoder: 25 MFMA LSTM steps + FC ===================
    for (int t = 0; t < PRED_LEN; t++){
        f32x4 acc[2][4];
        #pragma unroll
        for (int m = 0; m < 2; m++){
            #pragma unroll
            for (int j = 0; j < 4; j++){
                int s = 16*m + 4*qq + j;
                float p0 = sh_p0[s], p1 = sh_p1[s];
                #pragma unroll
                for (int nt = 0; nt < 4; nt++)
                    acc[m][nt][j] = bias_d[nt] + wd0[nt]*p0 + wd1[nt]*p1;
            }
        }
        #pragma unroll
        for (int kt = 0; kt < 2; kt++){
            #pragma unroll
            for (int m = 0; m < 2; m++){
                int idx = SWZ(16*m + lo15, 32*kt + 8*qq);
                short8 ah = *reinterpret_cast<const short8*>(&shA_hi[idx]);
                short8 al = *reinterpret_cast<const short8*>(&shA_lo[idx]);
                #pragma unroll
                for (int nt = 0; nt < 4; nt++){
                    acc[m][nt] = __builtin_amdgcn_mfma_f32_16x16x32_bf16(ah, dBh[nt][kt], acc[m][nt], 0,0,0);
                    acc[m][nt] = __builtin_amdgcn_mfma_f32_16x16x32_bf16(al, dBh[nt][kt], acc[m][nt], 0,0,0);
                    acc[m][nt] = __builtin_amdgcn_mfma_f32_16x16x32_bf16(ah, dBl[nt][kt], acc[m][nt], 0,0,0);
                }
            }
        }
        __syncthreads();   // A/p reads done before overwrite

        nonlin_store(acc, false);
        __syncthreads();   // h visible for FC

        if (tid < 176){
            int idx0 = SWZ(fs, 16*fq);
            int idx1 = SWZ(fs, 16*fq + 8);
            short8 h0h = *reinterpret_cast<const short8*>(&shA_hi[idx0]);
            short8 h0l = *reinterpret_cast<const short8*>(&shA_lo[idx0]);
            short8 h1h = *reinterpret_cast<const short8*>(&shA_hi[idx1]);
            short8 h1l = *reinterpret_cast<const short8*>(&shA_lo[idx1]);
            float part = 0.0f;
            #pragma unroll
            for (int e = 0; e < 8; e++){
                part = fmaf(bf_f((unsigned short)h0h[e]) + bf_f((unsigned short)h0l[e]), fcw[e],     part);
                part = fmaf(bf_f((unsigned short)h1h[e]) + bf_f((unsigned short)h1l[e]), fcw[8 + e], part);
            }
            part += __shfl_xor(part, 1);
            part += __shfl_xor(part, 2);
            if (fq == 0){
                float pred = part + fcb;
                outb[(fs*PRED_LEN + t)*OUT_DIM + fo] = pred;
                if (fo == 0) sh_p0[fs] = pred; else sh_p1[fs] = pred;
            }
        }
        __syncthreads();   // sh_p ready for next step
    }
}

extern "C" void kernel_launch(void* const* d_in, const int* in_sizes, int n_in,
                              void* d_out, int out_size, void* d_ws, size_t ws_size,
                              hipStream_t stream) {
    const float* x        = (const float*)d_in[0];
    const float* enc_Wih  = (const float*)d_in[1];
    const float* enc_Whh  = (const float*)d_in[2];
    const float* enc_bih  = (const float*)d_in[3];
    const float* enc_bhh  = (const float*)d_in[4];
    const float* q_W      = (const float*)d_in[5];
    const float* q_b      = (const float*)d_in[6];
    const float* k_W      = (const float*)d_in[7];
    const float* k_b      = (const float*)d_in[8];
    const float* v_W      = (const float*)d_in[9];
    const float* v_b      = (const float*)d_in[10];
    const float* ln_g     = (const float*)d_in[11];
    const float* ln_b     = (const float*)d_in[12];
    const float* dec_Wih  = (const float*)d_in[13];
    const float* dec_Whh  = (const float*)d_in[14];
    const float* dec_bih  = (const float*)d_in[15];
    const float* dec_bhh  = (const float*)d_in[16];
    const float* fc_W     = (const float*)d_in[17];
    const float* fc_b     = (const float*)d_in[18];
    float* out = (float*)d_out;

    nfl_mfma<<<dim3(NB), dim3(256), 0, stream>>>(
        x, enc_Wih, enc_Whh, enc_bih, enc_bhh,
        q_W, q_b, k_W, k_b, v_W, v_b, ln_g, ln_b,
        dec_Wih, dec_Whh, dec_bih, dec_bhh, fc_W, fc_b, out);
}

// Round 6
// 359.680 us; speedup vs baseline: 2.7188x; 1.0706x over previous
//
#include <hip/hip_runtime.h>

typedef short short8 __attribute__((ext_vector_type(8)));
typedef float f32x4 __attribute__((ext_vector_type(4)));

#define IN_DIM   33
#define HID      64
#define OUT_DIM  2
#define PRED_LEN 25
#define NB       1024
#define NP       22
#define NT       20
#define EPS      1e-5f

// swizzled element index into a [32][128] bf16 LDS tile (row stride 256B):
// XOR k with (s&7)<<3 spreads stride-256B columns across banks, keeps
// 8-element (16B) alignment for ds_read_b128.
#define SWZ(s,k) (((s) << 7) + ((k) ^ (((s) & 7) << 3)))

__device__ __forceinline__ float fast_rcp(float x){ return __builtin_amdgcn_rcpf(x); }
__device__ __forceinline__ float sigm(float x){ return fast_rcp(1.0f + __expf(-x)); }
__device__ __forceinline__ float tanhf_(float x){ float e = __expf(2.0f*x); return 1.0f - 2.0f*fast_rcp(e + 1.0f); }
// round-to-nearest-even f32 -> bf16 (scalar path, used in setup/staging)
__device__ __forceinline__ unsigned short bf_hi(float f){
    unsigned u = __float_as_uint(f);
    return (unsigned short)((u + 0x7fffu + ((u >> 16) & 1u)) >> 16);
}
__device__ __forceinline__ float bf_f(unsigned short h){ return __uint_as_float(((unsigned)h) << 16); }
// packed f32x2 -> bf16x2 (lo16 = bf16(a), hi16 = bf16(b)), RTNE
__device__ __forceinline__ unsigned cvt_pk_bf16(float a, float b){
    unsigned r;
    asm("v_cvt_pk_bf16_f32 %0, %1, %2" : "=v"(r) : "v"(a), "v"(b));
    return r;
}

// NOTE launch bounds: kernel keeps ~128 VGPRs of B-fragments live plus ~32
// accumulator regs (gfx950 unified VGPR/AGPR file) -> total ~156, which pins
// occupancy at 8 waves/CU (waves step at totals {64,128,256}, m69). (256,4)
// forced a 64-VGPR cap -> catastrophic scratch spill (R4: FETCH 2.4 GB).
// Keep (256,2); occupancy ~21% is structural for this design.
__global__ __launch_bounds__(256, 2) void nfl_mfma(
    const float* __restrict__ x,
    const float* __restrict__ enc_Wih, const float* __restrict__ enc_Whh,
    const float* __restrict__ enc_bih, const float* __restrict__ enc_bhh,
    const float* __restrict__ q_W, const float* __restrict__ q_b,
    const float* __restrict__ k_W, const float* __restrict__ k_b,
    const float* __restrict__ v_W, const float* __restrict__ v_b,
    const float* __restrict__ ln_g, const float* __restrict__ ln_b,
    const float* __restrict__ dec_Wih, const float* __restrict__ dec_Whh,
    const float* __restrict__ dec_bih, const float* __restrict__ dec_bhh,
    const float* __restrict__ fc_W, const float* __restrict__ fc_b,
    float* __restrict__ out)
{
    // A-tile arena, DOUBLE-BUFFERED: buf p at arena + p*16KB, each buf =
    // [32][128] u16 hi (8KB) + [32][128] u16 lo (8KB). Step t reads buf[t&1],
    // writes h(t) (and x(t+1)) into buf[1-(t&1)] -> ONE barrier per step.
    // During attention, K/V (fp32 [22][66]) alias buf1 (QKV MFMAs read buf0).
    __shared__ __align__(16) unsigned char arena[4*8192];
    __shared__ float sh_q [NP*66];
    __shared__ float sh_f [NP*66];
    __shared__ float sh_sc[NP*24];
    __shared__ float sh_p0[32];
    __shared__ float sh_p1[32];
    __shared__ float sh_mu[NP];
    __shared__ float sh_rs[NP];

    float* sh_k = (float*)(arena + 16384);          // alias buf1_hi, attn only
    float* sh_v = (float*)(arena + 16384 + 8192);   // alias buf1_lo, attn only

    const int tid  = threadIdx.x;
    const int w    = tid >> 6;        // wave id 0..3
    const int ln   = tid & 63;
    const int lo15 = ln & 15;
    const int qq   = ln >> 4;         // lane quarter 0..3
    const int jh   = 16*w + lo15;     // this lane's hidden column (0..63)
    const int b    = blockIdx.x;
    const float* xb = x + (size_t)b * NP*NT*IN_DIM;

    auto Ahi = [&](int p){ return (unsigned short*)(arena + p*16384); };
    auto Alo = [&](int p){ return (unsigned short*)(arena + p*16384 + 8192); };

    // ---- encoder B fragments in registers (split bf16) ----
    // B[k][g] = enc_Whh[g][k] (k<64) | enc_Wih[g][k-64] (k-64<33) | 0
    short8 eBh[4][4], eBl[4][4];
    float bias_e[4];
    #pragma unroll
    for (int nt = 0; nt < 4; nt++){
        int g = 16*w + 64*nt + lo15;
        bias_e[nt] = enc_bih[g] + enc_bhh[g];
        #pragma unroll
        for (int kt = 0; kt < 4; kt++){
            #pragma unroll
            for (int e = 0; e < 8; e++){
                int k = 32*kt + 8*qq + e;
                float v;
                if (k < HID) v = enc_Whh[g*HID + k];
                else { int d = k - HID; v = (d < IN_DIM) ? enc_Wih[g*IN_DIM + d] : 0.0f; }
                unsigned short h = bf_hi(v);
                eBh[nt][kt][e] = (short)h;
                eBl[nt][kt][e] = (short)bf_hi(v - bf_f(h));
            }
        }
    }

    // zero BOTH A buffers (padded rows 22..31 / cols 97..127 must stay zero)
    for (int i = tid; i < 4*2048; i += 256) ((unsigned*)arena)[i] = 0;

    float cst[2][4] = {{0,0,0,0},{0,0,0,0}};   // cell state, per-lane
    __syncthreads();

    // LSTM nonlinearity from in-register gates; h -> split bf16 into dst buf
    auto nonlin_store = [&](f32x4 (&acc)[2][4], unsigned short* wh,
                            unsigned short* wl, bool save_f){
        #pragma unroll
        for (int m = 0; m < 2; m++){
            #pragma unroll
            for (int jp = 0; jp < 2; jp++){
                const int j0 = 2*jp;
                float hh0, hh1;
                {
                    float gi=acc[m][0][j0], gf=acc[m][1][j0], gg=acc[m][2][j0], go=acc[m][3][j0];
                    float c = sigm(gf)*cst[m][j0] + sigm(gi)*tanhf_(gg);
                    cst[m][j0] = c;
                    hh0 = sigm(go)*tanhf_(c);
                }
                {
                    float gi=acc[m][0][j0+1], gf=acc[m][1][j0+1], gg=acc[m][2][j0+1], go=acc[m][3][j0+1];
                    float c = sigm(gf)*cst[m][j0+1] + sigm(gi)*tanhf_(gg);
                    cst[m][j0+1] = c;
                    hh1 = sigm(go)*tanhf_(c);
                }
                unsigned hp = cvt_pk_bf16(hh0, hh1);
                float r0 = hh0 - __uint_as_float(hp << 16);
                float r1 = hh1 - __uint_as_float(hp & 0xffff0000u);
                unsigned lp = cvt_pk_bf16(r0, r1);
                const int s0 = 16*m + 4*qq + j0;
                if (s0 < NP){
                    int i0 = SWZ(s0, jh);
                    wh[i0] = (unsigned short)hp;
                    wl[i0] = (unsigned short)lp;
                    if (save_f) sh_f[s0*66 + jh] = hh0;
                }
                if (s0 + 1 < NP){
                    int i1 = SWZ(s0 + 1, jh);
                    wh[i1] = (unsigned short)(hp >> 16);
                    wl[i1] = (unsigned short)(lp >> 16);
                    if (save_f) sh_f[(s0+1)*66 + jh] = hh1;
                }
            }
        }
    };

    // =================== encoder: 20 MFMA LSTM steps ===================
    {   // prologue: stage x(0) into buf0 straight from global
        unsigned short* wh = Ahi(0); unsigned short* wl = Alo(0);
        for (int i = tid; i < NP*IN_DIM; i += 256){
            int s = i / IN_DIM, d = i - s * IN_DIM;
            float v = xb[(s*NT + 0)*IN_DIM + d];
            unsigned short h = bf_hi(v);
            int idx = SWZ(s, HID + d);
            wh[idx] = h; wl[idx] = bf_hi(v - bf_f(h));
        }
    }
    __syncthreads();

    for (int t = 0; t < NT; t++){
        const int p = t & 1;
        unsigned short* rh = Ahi(p);     unsigned short* rl = Alo(p);
        unsigned short* wh = Ahi(1 - p); unsigned short* wl = Alo(1 - p);

        // prefetch x(t+1) into registers (latency hides under the MFMAs)
        float xr[3];
        const bool have_x = (t + 1 < NT);
        if (have_x){
            #pragma unroll
            for (int sl = 0; sl < 3; sl++){
                int i = tid + 256*sl;
                if (i < NP*IN_DIM){
                    int s = i / IN_DIM, d = i - s * IN_DIM;
                    xr[sl] = xb[(s*NT + (t+1))*IN_DIM + d];
                }
            }
        }

        f32x4 acc[2][4];
        #pragma unroll
        for (int m = 0; m < 2; m++)
            #pragma unroll
            for (int nt = 0; nt < 4; nt++){
                float bb = bias_e[nt];
                acc[m][nt][0]=bb; acc[m][nt][1]=bb; acc[m][nt][2]=bb; acc[m][nt][3]=bb;
            }
        #pragma unroll
        for (int kt = 0; kt < 4; kt++){
            #pragma unroll
            for (int m = 0; m < 2; m++){
                int idx = SWZ(16*m + lo15, 32*kt + 8*qq);
                short8 ah = *reinterpret_cast<const short8*>(&rh[idx]);
                short8 al = *reinterpret_cast<const short8*>(&rl[idx]);
                #pragma unroll
                for (int nt = 0; nt < 4; nt++){
                    acc[m][nt] = __builtin_amdgcn_mfma_f32_16x16x32_bf16(ah, eBh[nt][kt], acc[m][nt], 0,0,0);
                    acc[m][nt] = __builtin_amdgcn_mfma_f32_16x16x32_bf16(al, eBh[nt][kt], acc[m][nt], 0,0,0);
                    acc[m][nt] = __builtin_amdgcn_mfma_f32_16x16x32_bf16(ah, eBl[nt][kt], acc[m][nt], 0,0,0);
                }
            }
        }
        // no barrier: reads hit buf[p], writes go to buf[1-p] (all waves
        // finished reading buf[1-p] before the PREVIOUS step's barrier).
        nonlin_store(acc, wh, wl, t == NT-1);
        if (have_x){
            #pragma unroll
            for (int sl = 0; sl < 3; sl++){
                int i = tid + 256*sl;
                if (i < NP*IN_DIM){
                    int s = i / IN_DIM, d = i - s * IN_DIM;
                    unsigned short h = bf_hi(xr[sl]);
                    int idx = SWZ(s, HID + d);
                    wh[idx] = h; wl[idx] = bf_hi(xr[sl] - bf_f(h));
                }
            }
        }
        __syncthreads();                 // h(t) (and x(t+1)) visible in buf[1-p]
    }

    // =================== attention: QKV via MFMA (reads buf0) ===================
    {
        unsigned short* rh = Ahi(0); unsigned short* rl = Alo(0);
        short8 qBh[3][2], qBl[3][2];
        float qb3[3];
        #pragma unroll
        for (int mat = 0; mat < 3; mat++){
            const float* W  = (mat==0) ? q_W : (mat==1) ? k_W : v_W;
            const float* bb = (mat==0) ? q_b : (mat==1) ? k_b : v_b;
            qb3[mat] = bb[jh];
            #pragma unroll
            for (int kt = 0; kt < 2; kt++){
                #pragma unroll
                for (int e = 0; e < 8; e++){
                    int k = 32*kt + 8*qq + e;
                    float v = W[jh*HID + k];
                    unsigned short h = bf_hi(v);
                    qBh[mat][kt][e] = (short)h;
                    qBl[mat][kt][e] = (short)bf_hi(v - bf_f(h));
                }
            }
        }
        f32x4 qacc[3][2];
        #pragma unroll
        for (int mat = 0; mat < 3; mat++)
            #pragma unroll
            for (int m = 0; m < 2; m++){
                float bb = qb3[mat];
                qacc[mat][m][0]=bb; qacc[mat][m][1]=bb; qacc[mat][m][2]=bb; qacc[mat][m][3]=bb;
            }
        #pragma unroll
        for (int kt = 0; kt < 2; kt++){
            #pragma unroll
            for (int m = 0; m < 2; m++){
                int idx = SWZ(16*m + lo15, 32*kt + 8*qq);
                short8 ah = *reinterpret_cast<const short8*>(&rh[idx]);
                short8 al = *reinterpret_cast<const short8*>(&rl[idx]);
                #pragma unroll
                for (int mat = 0; mat < 3; mat++){
                    qacc[mat][m] = __builtin_amdgcn_mfma_f32_16x16x32_bf16(ah, qBh[mat][kt], qacc[mat][m], 0,0,0);
                    qacc[mat][m] = __builtin_amdgcn_mfma_f32_16x16x32_bf16(al, qBh[mat][kt], qacc[mat][m], 0,0,0);
                    qacc[mat][m] = __builtin_amdgcn_mfma_f32_16x16x32_bf16(ah, qBl[mat][kt], qacc[mat][m], 0,0,0);
                }
            }
        }
        // K/V stores go to buf1 (not read by anyone since last barrier);
        // no barrier needed before them.
        #pragma unroll
        for (int mat = 0; mat < 3; mat++){
            float* dst = (mat==0) ? sh_q : (mat==1) ? sh_k : sh_v;
            #pragma unroll
            for (int m = 0; m < 2; m++)
                #pragma unroll
                for (int j = 0; j < 4; j++){
                    int s = 16*m + 4*qq + j;
                    if (s < NP) dst[s*66 + jh] = qacc[mat][m][j];
                }
        }
    }
    __syncthreads();

    // scores = QK^T / 8
    for (int i = tid; i < NP*NP; i += 256){
        int p = i / NP, q = i - p*NP;
        float acc = 0.0f;
        #pragma unroll
        for (int k = 0; k < HID; k++) acc = fmaf(sh_q[p*66 + k], sh_k[q*66 + k], acc);
        sh_sc[p*24 + q] = acc * 0.125f;
    }
    __syncthreads();

    if (tid < NP){
        float m = -1e30f;
        for (int q = 0; q < NP; q++) m = fmaxf(m, sh_sc[tid*24 + q]);
        float sum = 0.0f;
        for (int q = 0; q < NP; q++){ float e = __expf(sh_sc[tid*24 + q] - m); sh_sc[tid*24 + q] = e; sum += e; }
        float inv = fast_rcp(sum);
        for (int q = 0; q < NP; q++) sh_sc[tid*24 + q] *= inv;
    }
    __syncthreads();

    // y = h + attn@V  (in place into sh_f)
    for (int i = tid; i < NP*HID; i += 256){
        int s = i >> 6, j = i & 63;
        float acc = 0.0f;
        #pragma unroll
        for (int q = 0; q < NP; q++) acc = fmaf(sh_sc[s*24 + q], sh_v[q*66 + j], acc);
        sh_f[s*66 + j] += acc;
    }
    __syncthreads();

    // layernorm stats
    if (tid < NP){
        float mu = 0.0f;
        for (int j = 0; j < HID; j++) mu += sh_f[tid*66 + j];
        mu *= (1.0f/HID);
        float var = 0.0f;
        for (int j = 0; j < HID; j++){ float d = sh_f[tid*66 + j] - mu; var += d*d; }
        sh_mu[tid] = mu;
        sh_rs[tid] = rsqrtf(var*(1.0f/HID) + EPS);
    }
    __syncthreads();

    // LN apply -> decoder h0 into buf0 (split bf16, packed u32 stores).
    // buf1 rows <=22 hold K/V garbage; decoder consumes only cols<64 (K=64)
    // and discards output rows >=22, and buf rows 23..31 are still zero.
    {
        unsigned short* wh = Ahi(0); unsigned short* wl = Alo(0);
        for (int i = tid; i < NP*HID/2; i += 256){
            int s = i >> 5, j0 = (i & 31) << 1;
            float sc = sh_rs[s], mu = sh_mu[s];
            float v0 = (sh_f[s*66 + j0]   - mu) * sc * ln_g[j0]   + ln_b[j0];
            float v1 = (sh_f[s*66 + j0+1] - mu) * sc * ln_g[j0+1] + ln_b[j0+1];
            unsigned hp = cvt_pk_bf16(v0, v1);
            float r0 = v0 - __uint_as_float(hp << 16);
            float r1 = v1 - __uint_as_float(hp & 0xffff0000u);
            unsigned lp = cvt_pk_bf16(r0, r1);
            int idx = SWZ(s, j0);   // j0 even -> idx even -> 4B aligned
            *(unsigned*)&wh[idx] = hp;
            *(unsigned*)&wl[idx] = lp;
        }
    }
    if (tid < 32){
        float v0 = 0.0f, v1 = 0.0f;
        if (tid < NP){
            v0 = xb[(tid*NT + NT-1)*IN_DIM + 0];
            v1 = xb[(tid*NT + NT-1)*IN_DIM + 1];
        }
        sh_p0[tid] = v0; sh_p1[tid] = v1;
    }

    // ---- decoder B fragments + FC weights ----
    short8 dBh[4][2], dBl[4][2];
    float bias_d[4], wd0[4], wd1[4];
    #pragma unroll
    for (int nt = 0; nt < 4; nt++){
        int g = 16*w + 64*nt + lo15;
        bias_d[nt] = dec_bih[g] + dec_bhh[g];
        wd0[nt] = dec_Wih[g*OUT_DIM + 0];
        wd1[nt] = dec_Wih[g*OUT_DIM + 1];
        #pragma unroll
        for (int kt = 0; kt < 2; kt++){
            #pragma unroll
            for (int e = 0; e < 8; e++){
                int k = 32*kt + 8*qq + e;
                float v = dec_Whh[g*HID + k];
                unsigned short h = bf_hi(v);
                dBh[nt][kt][e] = (short)h;
                dBl[nt][kt][e] = (short)bf_hi(v - bf_f(h));
            }
        }
    }
    const int fitem = tid >> 2, fq = tid & 3, fs = fitem >> 1, fo = fitem & 1;
    float fcw[16]; float fcb = 0.0f;
    if (tid < 176){
        #pragma unroll
        for (int jj = 0; jj < 16; jj++) fcw[jj] = fc_W[fo*HID + 16*fq + jj];
        fcb = fc_b[fo];
    }
    float* outb = out + (size_t)b * NP * PRED_LEN * OUT_DIM;
    __syncthreads();

    // =================== decoder: 25 MFMA LSTM steps + FC ===================
    for (int t = 0; t < PRED_LEN; t++){
        const int p = t & 1;
        unsigned short* rh = Ahi(p);     unsigned short* rl = Alo(p);
        unsigned short* wh = Ahi(1 - p); unsigned short* wl = Alo(1 - p);

        f32x4 acc[2][4];
        #pragma unroll
        for (int m = 0; m < 2; m++){
            #pragma unroll
            for (int j = 0; j < 4; j++){
                int s = 16*m + 4*qq + j;
                float p0 = sh_p0[s], p1 = sh_p1[s];
                #pragma unroll
                for (int nt = 0; nt < 4; nt++)
                    acc[m][nt][j] = bias_d[nt] + wd0[nt]*p0 + wd1[nt]*p1;
            }
        }
        #pragma unroll
        for (int kt = 0; kt < 2; kt++){
            #pragma unroll
            for (int m = 0; m < 2; m++){
                int idx = SWZ(16*m + lo15, 32*kt + 8*qq);
                short8 ah = *reinterpret_cast<const short8*>(&rh[idx]);
                short8 al = *reinterpret_cast<const short8*>(&rl[idx]);
                #pragma unroll
                for (int nt = 0; nt < 4; nt++){
                    acc[m][nt] = __builtin_amdgcn_mfma_f32_16x16x32_bf16(ah, dBh[nt][kt], acc[m][nt], 0,0,0);
                    acc[m][nt] = __builtin_amdgcn_mfma_f32_16x16x32_bf16(al, dBh[nt][kt], acc[m][nt], 0,0,0);
                    acc[m][nt] = __builtin_amdgcn_mfma_f32_16x16x32_bf16(ah, dBl[nt][kt], acc[m][nt], 0,0,0);
                }
            }
        }
        // no barrier: reads hit buf[p] (+sh_p), writes go to buf[1-p]
        nonlin_store(acc, wh, wl, false);
        __syncthreads();   // h(t) visible for FC; sh_p reads done

        if (tid < 176){
            int idx0 = SWZ(fs, 16*fq);
            int idx1 = SWZ(fs, 16*fq + 8);
            short8 h0h = *reinterpret_cast<const short8*>(&wh[idx0]);
            short8 h0l = *reinterpret_cast<const short8*>(&wl[idx0]);
            short8 h1h = *reinterpret_cast<const short8*>(&wh[idx1]);
            short8 h1l = *reinterpret_cast<const short8*>(&wl[idx1]);
            float part = 0.0f;
            #pragma unroll
            for (int e = 0; e < 8; e++){
                part = fmaf(bf_f((unsigned short)h0h[e]) + bf_f((unsigned short)h0l[e]), fcw[e],     part);
                part = fmaf(bf_f((unsigned short)h1h[e]) + bf_f((unsigned short)h1l[e]), fcw[8 + e], part);
            }
            part += __shfl_xor(part, 1);
            part += __shfl_xor(part, 2);
            if (fq == 0){
                float pred = part + fcb;
                outb[(fs*PRED_LEN + t)*OUT_DIM + fo] = pred;
                if (fo == 0) sh_p0[fs] = pred; else sh_p1[fs] = pred;
            }
        }
        __syncthreads();   // sh_p ready for next step
    }
}

extern "C" void kernel_launch(void* const* d_in, const int* in_sizes, int n_in,
                              void* d_out, int out_size, void* d_ws, size_t ws_size,
                              hipStream_t stream) {
    const float* x        = (const float*)d_in[0];
    const float* enc_Wih  = (const float*)d_in[1];
    const float* enc_Whh  = (const float*)d_in[2];
    const float* enc_bih  = (const float*)d_in[3];
    const float* enc_bhh  = (const float*)d_in[4];
    const float* q_W      = (const float*)d_in[5];
    const float* q_b      = (const float*)d_in[6];
    const float* k_W      = (const float*)d_in[7];
    const float* k_b      = (const float*)d_in[8];
    const float* v_W      = (const float*)d_in[9];
    const float* v_b      = (const float*)d_in[10];
    const float* ln_g     = (const float*)d_in[11];
    const float* ln_b     = (const float*)d_in[12];
    const float* dec_Wih  = (const float*)d_in[13];
    const float* dec_Whh  = (const float*)d_in[14];
    const float* dec_bih  = (const float*)d_in[15];
    const float* dec_bhh  = (const float*)d_in[16];
    const float* fc_W     = (const float*)d_in[17];
    const float* fc_b     = (const float*)d_in[18];
    float* out = (float*)d_out;

    nfl_mfma<<<dim3(NB), dim3(256), 0, stream>>>(
        x, enc_Wih, enc_Whh, enc_bih, enc_bhh,
        q_W, q_b, k_W, k_b, v_W, v_b, ln_g, ln_b,
        dec_Wih, dec_Whh, dec_bih, dec_bhh, fc_W, fc_b, out);
}

// Round 10
// 339.629 us; speedup vs baseline: 2.8793x; 1.0590x over previous
//
#include <hip/hip_runtime.h>

typedef short short8 __attribute__((ext_vector_type(8)));
typedef float f32x4 __attribute__((ext_vector_type(4)));

#define IN_DIM   33
#define HID      64
#define OUT_DIM  2
#define PRED_LEN 25
#define NB       1024
#define NP       22
#define NT       20
#define EPS      1e-5f
#define QSTR     65      // sh_q / K / V row stride (floats); 65%32==1 -> conflict-free

// swizzled element index into a [48][128] bf16 LDS plane (row stride 256B):
// XOR k with (s&7)<<3 (touches bits 3..5 only, so cols>=64 stay >=64).
#define SWZ(s,k) (((s) << 7) + ((k) ^ (((s) & 7) << 3)))

__device__ __forceinline__ float fast_rcp(float x){ return __builtin_amdgcn_rcpf(x); }
__device__ __forceinline__ float sigm(float x){ return fast_rcp(1.0f + __expf(-x)); }
__device__ __forceinline__ float tanhf_(float x){ float e = __expf(2.0f*x); return 1.0f - 2.0f*fast_rcp(e + 1.0f); }
__device__ __forceinline__ unsigned short bf_hi(float f){
    unsigned u = __float_as_uint(f);
    return (unsigned short)((u + 0x7fffu + ((u >> 16) & 1u)) >> 16);
}
__device__ __forceinline__ float bf_f(unsigned short h){ return __uint_as_float(((unsigned)h) << 16); }
__device__ __forceinline__ unsigned cvt_pk_bf16(float a, float b){
    unsigned r;
    asm("v_cvt_pk_bf16_f32 %0, %1, %2" : "=v"(r) : "v"(a), "v"(b));
    return r;
}

// NOTE launch bounds: ~128 VGPRs of B-fragments + ~48 acc + misc live in the
// encoder (gfx950 unified VGPR/AGPR file) -> 2 waves/SIMD (256-reg budget).
// (256,4) forced a 64-VGPR cap -> catastrophic scratch spill (R4). Keep (256,2).
__global__ __launch_bounds__(256, 2) void nfl_mfma(
    const float* __restrict__ x,
    const float* __restrict__ enc_Wih, const float* __restrict__ enc_Whh,
    const float* __restrict__ enc_bih, const float* __restrict__ enc_bhh,
    const float* __restrict__ q_W, const float* __restrict__ q_b,
    const float* __restrict__ k_W, const float* __restrict__ k_b,
    const float* __restrict__ v_W, const float* __restrict__ v_b,
    const float* __restrict__ ln_g, const float* __restrict__ ln_b,
    const float* __restrict__ dec_Wih, const float* __restrict__ dec_Whh,
    const float* __restrict__ dec_bih, const float* __restrict__ dec_bhh,
    const float* __restrict__ fc_W, const float* __restrict__ fc_b,
    float* __restrict__ out)
{
    // TWO batches per block: A-tile rows 0..21 = batch0, 24..45 = batch1,
    // rows 22,23,46,47 padding. Double-buffered A: buf p at arena + p*24576,
    // each buf = hi plane (48x128 u16 = 12KB) + lo plane (12KB).
    // Dead-space reuse (cols 64..127 are swizzle-invariant as a range):
    //  - scores/mu/rs live in buf0 hi-plane float chunks [r*64+32, r*64+64)
    //  - decoder feedback p0/p1 live in buf1 hi-plane chunks (+32/+33)
    //  - K,V (fp32 [44][QSTR]) alias buf1 during attention only
    __shared__ __align__(16) unsigned char arena[2*24576];
    __shared__ float sh_q[44*QSTR];   // Q, then y (residual+ctx)

    float* arena_f = (float*)arena;
    float* sh_k = (float*)(arena + 24576);
    float* sh_v = sh_k + 44*QSTR;     // byte 36016, 16B aligned

    const int tid  = threadIdx.x;
    const int w    = tid >> 6;
    const int ln   = tid & 63;
    const int lo15 = ln & 15;
    const int qq   = ln >> 4;
    const int jh   = 16*w + lo15;     // this lane's hidden column (0..63)
    const int bid  = blockIdx.x;
    const float* xb0 = x + (size_t)(2*bid) * NP*NT*IN_DIM;
    const float* xb1 = xb0 + NP*NT*IN_DIM;

    auto Ahi = [&](int p){ return (unsigned short*)(arena + p*24576); };
    auto Alo = [&](int p){ return (unsigned short*)(arena + p*24576 + 12288); };

    // ---- encoder B fragments in registers (split bf16) ----
    short8 eBh[4][4], eBl[4][4];
    float bias_e[4];
    #pragma unroll
    for (int nt = 0; nt < 4; nt++){
        int g = 16*w + 64*nt + lo15;
        bias_e[nt] = enc_bih[g] + enc_bhh[g];
        #pragma unroll
        for (int kt = 0; kt < 4; kt++){
            #pragma unroll
            for (int e = 0; e < 8; e++){
                int k = 32*kt + 8*qq + e;
                float v;
                if (k < HID) v = enc_Whh[g*HID + k];
                else { int d = k - HID; v = (d < IN_DIM) ? enc_Wih[g*IN_DIM + d] : 0.0f; }
                unsigned short h = bf_hi(v);
                eBh[nt][kt][e] = (short)h;
                eBl[nt][kt][e] = (short)bf_hi(v - bf_f(h));
            }
        }
    }

    // zero both A buffers (padding rows/cols must start zero)
    for (int i = tid; i < 12288; i += 256) ((unsigned*)arena)[i] = 0;

    float cst[3][4];
    #pragma unroll
    for (int mt = 0; mt < 3; mt++)
        #pragma unroll
        for (int j = 0; j < 4; j++) cst[mt][j] = 0.0f;
    __syncthreads();

    // x_t staging for both batches into cols 64..96 of dst buf
    auto stage_x_regs = [&](int t, float (&xr)[6]){
        #pragma unroll
        for (int sl = 0; sl < 6; sl++){
            int i = tid + 256*sl;
            if (i < 2*NP*IN_DIM){
                int bb = (i >= NP*IN_DIM);
                int rem = i - bb*NP*IN_DIM;
                int s = rem / IN_DIM, d = rem - s*IN_DIM;
                const float* xb = bb ? xb1 : xb0;
                xr[sl] = xb[(s*NT + t)*IN_DIM + d];
            }
        }
    };
    auto stage_x_write = [&](float (&xr)[6], unsigned short* wh, unsigned short* wl){
        #pragma unroll
        for (int sl = 0; sl < 6; sl++){
            int i = tid + 256*sl;
            if (i < 2*NP*IN_DIM){
                int bb = (i >= NP*IN_DIM);
                int rem = i - bb*NP*IN_DIM;
                int s = rem / IN_DIM, d = rem - s*IN_DIM;
                unsigned short h = bf_hi(xr[sl]);
                int idx = SWZ(bb*24 + s, HID + d);
                wh[idx] = h; wl[idx] = bf_hi(xr[sl] - bf_f(h));
            }
        }
    };

    // LSTM nonlinearity; h -> split bf16 into dst buf (valid rows only)
    auto nonlin_store = [&](f32x4 (&acc)[3][4], unsigned short* wh, unsigned short* wl){
        #pragma unroll
        for (int mt = 0; mt < 3; mt++){
            #pragma unroll
            for (int jp = 0; jp < 2; jp++){
                const int j0 = 2*jp;
                float hh0, hh1;
                {
                    float gi=acc[mt][0][j0], gf=acc[mt][1][j0], gg=acc[mt][2][j0], go=acc[mt][3][j0];
                    float c = sigm(gf)*cst[mt][j0] + sigm(gi)*tanhf_(gg);
                    cst[mt][j0] = c;
                    hh0 = sigm(go)*tanhf_(c);
                }
                {
                    float gi=acc[mt][0][j0+1], gf=acc[mt][1][j0+1], gg=acc[mt][2][j0+1], go=acc[mt][3][j0+1];
                    float c = sigm(gf)*cst[mt][j0+1] + sigm(gi)*tanhf_(gg);
                    cst[mt][j0+1] = c;
                    hh1 = sigm(go)*tanhf_(c);
                }
                unsigned hp = cvt_pk_bf16(hh0, hh1);
                float r0 = hh0 - __uint_as_float(hp << 16);
                float r1 = hh1 - __uint_as_float(hp & 0xffff0000u);
                unsigned lp = cvt_pk_bf16(r0, r1);
                const int s0 = 16*mt + 4*qq + j0;
                const int ps0 = s0 - ((s0 >= 24) ? 24 : 0);
                if (ps0 < NP){
                    int i0 = SWZ(s0, jh);
                    wh[i0] = (unsigned short)hp;
                    wl[i0] = (unsigned short)lp;
                }
                if (ps0 + 1 < NP){   // pairs never straddle the batch boundary
                    int i1 = SWZ(s0 + 1, jh);
                    wh[i1] = (unsigned short)(hp >> 16);
                    wl[i1] = (unsigned short)(lp >> 16);
                }
            }
        }
    };

    // =================== encoder: 20 MFMA LSTM steps ===================
    {
        float xr[6];
        stage_x_regs(0, xr);
        stage_x_write(xr, Ahi(0), Alo(0));
    }
    __syncthreads();

    for (int t = 0; t < NT; t++){
        const int p = t & 1;
        unsigned short* rh = Ahi(p);     unsigned short* rl = Alo(p);
        unsigned short* wh = Ahi(1 - p); unsigned short* wl = Alo(1 - p);

        float xr[6];
        const bool have_x = (t + 1 < NT);
        if (have_x) stage_x_regs(t + 1, xr);

        f32x4 acc[3][4];
        #pragma unroll
        for (int mt = 0; mt < 3; mt++)
            #pragma unroll
            for (int nt = 0; nt < 4; nt++){
                float bb = bias_e[nt];
                acc[mt][nt][0]=bb; acc[mt][nt][1]=bb; acc[mt][nt][2]=bb; acc[mt][nt][3]=bb;
            }
        #pragma unroll
        for (int kt = 0; kt < 4; kt++){
            #pragma unroll
            for (int mt = 0; mt < 3; mt++){
                int idx = SWZ(16*mt + lo15, 32*kt + 8*qq);
                short8 ah = *reinterpret_cast<const short8*>(&rh[idx]);
                short8 al = *reinterpret_cast<const short8*>(&rl[idx]);
                #pragma unroll
                for (int nt = 0; nt < 4; nt++){
                    acc[mt][nt] = __builtin_amdgcn_mfma_f32_16x16x32_bf16(ah, eBh[nt][kt], acc[mt][nt], 0,0,0);
                    acc[mt][nt] = __builtin_amdgcn_mfma_f32_16x16x32_bf16(al, eBh[nt][kt], acc[mt][nt], 0,0,0);
                    acc[mt][nt] = __builtin_amdgcn_mfma_f32_16x16x32_bf16(ah, eBl[nt][kt], acc[mt][nt], 0,0,0);
                }
            }
        }
        // reads hit buf[p]; writes go to buf[1-p] -> no mid-step barrier
        nonlin_store(acc, wh, wl);
        if (have_x) stage_x_write(xr, wh, wl);
        __syncthreads();
    }

    // =================== attention: QKV via MFMA (reads buf0) ===================
    {
        unsigned short* rh = Ahi(0); unsigned short* rl = Alo(0);
        short8 qBh[3][2], qBl[3][2];
        float qb3[3];
        #pragma unroll
        for (int mat = 0; mat < 3; mat++){
            const float* W  = (mat==0) ? q_W : (mat==1) ? k_W : v_W;
            const float* bb = (mat==0) ? q_b : (mat==1) ? k_b : v_b;
            qb3[mat] = bb[jh];
            #pragma unroll
            for (int kt = 0; kt < 2; kt++){
                #pragma unroll
                for (int e = 0; e < 8; e++){
                    int k = 32*kt + 8*qq + e;
                    float v = W[jh*HID + k];
                    unsigned short h = bf_hi(v);
                    qBh[mat][kt][e] = (short)h;
                    qBl[mat][kt][e] = (short)bf_hi(v - bf_f(h));
                }
            }
        }
        f32x4 qacc[3][3];
        #pragma unroll
        for (int mat = 0; mat < 3; mat++)
            #pragma unroll
            for (int mt = 0; mt < 3; mt++){
                float bb = qb3[mat];
                qacc[mat][mt][0]=bb; qacc[mat][mt][1]=bb; qacc[mat][mt][2]=bb; qacc[mat][mt][3]=bb;
            }
        #pragma unroll
        for (int kt = 0; kt < 2; kt++){
            #pragma unroll
            for (int mt = 0; mt < 3; mt++){
                int idx = SWZ(16*mt + lo15, 32*kt + 8*qq);
                short8 ah = *reinterpret_cast<const short8*>(&rh[idx]);
                short8 al = *reinterpret_cast<const short8*>(&rl[idx]);
                #pragma unroll
                for (int mat = 0; mat < 3; mat++){
                    qacc[mat][mt] = __builtin_amdgcn_mfma_f32_16x16x32_bf16(ah, qBh[mat][kt], qacc[mat][mt], 0,0,0);
                    qacc[mat][mt] = __builtin_amdgcn_mfma_f32_16x16x32_bf16(al, qBh[mat][kt], qacc[mat][mt], 0,0,0);
                    qacc[mat][mt] = __builtin_amdgcn_mfma_f32_16x16x32_bf16(ah, qBl[mat][kt], qacc[mat][mt], 0,0,0);
                }
            }
        }
        // K/V overwrite buf1 (dead since last barrier); Q -> sh_q
        #pragma unroll
        for (int mat = 0; mat < 3; mat++){
            float* dst = (mat==0) ? sh_q : (mat==1) ? sh_k : sh_v;
            #pragma unroll
            for (int mt = 0; mt < 3; mt++)
                #pragma unroll
                for (int j = 0; j < 4; j++){
                    int s = 16*mt + 4*qq + j;
                    int bb = (s >= 24) ? 1 : 0;
                    int ps = s - 24*bb;
                    if (ps < NP) dst[(bb*NP + ps)*QSTR + jh] = qacc[mat][mt][j];
                }
        }
    }
    __syncthreads();

    // scores = QK^T / 8 -> buf0 dead chunks: arena_f[(bb*24+p)*64 + 32 + q]
    for (int i = tid; i < 2*NP*NP; i += 256){
        int bb = (i >= NP*NP);
        int rem = i - bb*NP*NP;
        int p = rem / NP, q = rem - p*NP;
        float acc = 0.0f;
        #pragma unroll
        for (int k = 0; k < HID; k++)
            acc = fmaf(sh_q[(bb*NP + p)*QSTR + k], sh_k[(bb*NP + q)*QSTR + k], acc);
        arena_f[(bb*24 + p)*64 + 32 + q] = acc * 0.125f;
    }
    __syncthreads();

    // softmax per row (44 rows)
    if (tid < 2*NP){
        int bb = (tid >= NP);
        int p = tid - bb*NP;
        float* row = arena_f + (bb*24 + p)*64 + 32;
        float m = -1e30f;
        for (int q = 0; q < NP; q++) m = fmaxf(m, row[q]);
        float sum = 0.0f;
        for (int q = 0; q < NP; q++){ float e = __expf(row[q] - m); row[q] = e; sum += e; }
        float inv = fast_rcp(sum);
        for (int q = 0; q < NP; q++) row[q] *= inv;
    }
    __syncthreads();

    // y = h + attn@V -> sh_q (Q dead); h reconstructed from buf0 hi+lo
    {
        unsigned short* h0 = Ahi(0); unsigned short* l0 = Alo(0);
        for (int i = tid; i < 2*NP*HID; i += 256){
            int bb = (i >= NP*HID);
            int rem = i - bb*NP*HID;
            int ps = rem >> 6, j = rem & 63;
            int r = bb*24 + ps;
            const float* sc = arena_f + r*64 + 32;
            float acc = 0.0f;
            #pragma unroll
            for (int q = 0; q < NP; q++) acc = fmaf(sc[q], sh_v[(bb*NP + q)*QSTR + j], acc);
            int idx = SWZ(r, j);
            float h = bf_f(h0[idx]) + bf_f(l0[idx]);
            sh_q[(bb*NP + ps)*QSTR + j] = h + acc;
        }
    }
    __syncthreads();

    // layernorm stats -> chunk slots +22 (mu), +23 (rs)
    if (tid < 2*NP){
        int bb = (tid >= NP);
        int ps = tid - bb*NP;
        const float* yrow = sh_q + (bb*NP + ps)*QSTR;
        float mu = 0.0f;
        for (int j = 0; j < HID; j++) mu += yrow[j];
        mu *= (1.0f/HID);
        float var = 0.0f;
        for (int j = 0; j < HID; j++){ float d = yrow[j] - mu; var += d*d; }
        arena_f[(bb*24 + ps)*64 + 32 + 22] = mu;
        arena_f[(bb*24 + ps)*64 + 32 + 23] = rsqrtf(var*(1.0f/HID) + EPS);
    }
    __syncthreads();

    // LN apply -> decoder h0 into buf0 (split bf16, packed u32 stores)
    {
        unsigned short* wh = Ahi(0); unsigned short* wl = Alo(0);
        for (int i = tid; i < 2*NP*HID/2; i += 256){
            int bb = (i >= NP*HID/2);
            int rem = i - bb*NP*HID/2;
            int ps = rem >> 5, j0 = (rem & 31) << 1;
            int r = bb*24 + ps;
            float mu = arena_f[r*64 + 32 + 22];
            float sc = arena_f[r*64 + 32 + 23];
            const float* yrow = sh_q + (bb*NP + ps)*QSTR;
            float v0 = (yrow[j0]   - mu) * sc * ln_g[j0]   + ln_b[j0];
            float v1 = (yrow[j0+1] - mu) * sc * ln_g[j0+1] + ln_b[j0+1];
            unsigned hp = cvt_pk_bf16(v0, v1);
            float r0 = v0 - __uint_as_float(hp << 16);
            float r1 = v1 - __uint_as_float(hp & 0xffff0000u);
            unsigned lp = cvt_pk_bf16(r0, r1);
            int idx = SWZ(r, j0);
            *(unsigned*)&wh[idx] = hp;
            *(unsigned*)&wl[idx] = lp;
        }
    }
    // decoder feedback init: p0/p1 slots in buf1 hi-plane dead chunks
    if (tid < 48){
        int bb = (tid >= 24);
        int ps = tid - 24*bb;
        float v0 = 0.0f, v1 = 0.0f;
        if (ps < NP){
            const float* xb = bb ? xb1 : xb0;
            v0 = xb[(ps*NT + NT-1)*IN_DIM + 0];
            v1 = xb[(ps*NT + NT-1)*IN_DIM + 1];
        }
        arena_f[6144 + tid*64 + 32] = v0;
        arena_f[6144 + tid*64 + 33] = v1;
    }

    // ---- decoder B fragments + FC weights ----
    short8 dBh[4][2], dBl[4][2];
    float bias_d[4], wd0[4], wd1[4];
    #pragma unroll
    for (int nt = 0; nt < 4; nt++){
        int g = 16*w + 64*nt + lo15;
        bias_d[nt] = dec_bih[g] + dec_bhh[g];
        wd0[nt] = dec_Wih[g*OUT_DIM + 0];
        wd1[nt] = dec_Wih[g*OUT_DIM + 1];
        #pragma unroll
        for (int kt = 0; kt < 2; kt++){
            #pragma unroll
            for (int e = 0; e < 8; e++){
                int k = 32*kt + 8*qq + e;
                float v = dec_Whh[g*HID + k];
                unsigned short h = bf_hi(v);
                dBh[nt][kt][e] = (short)h;
                dBl[nt][kt][e] = (short)bf_hi(v - bf_f(h));
            }
        }
    }
    // FC: 88 outputs (2 batches x 22 seq x 2), 2 lanes each (fq halves of HID)
    const int fitem = tid >> 1, fq = tid & 1;
    const int fbb = fitem / 44, frem = fitem - fbb*44, fs = frem >> 1, fo = frem & 1;
    float fcw[32]; float fcb = 0.0f;
    if (tid < 176){
        #pragma unroll
        for (int jj = 0; jj < 32; jj++) fcw[jj] = fc_W[fo*HID + 32*fq + jj];
        fcb = fc_b[fo];
    }
    float* outb0 = out + (size_t)(2*bid) * NP * PRED_LEN * OUT_DIM;
    float* outb1 = outb0 + NP * PRED_LEN * OUT_DIM;
    __syncthreads();

    // =================== decoder: 25 MFMA LSTM steps + FC ===================
    for (int t = 0; t < PRED_LEN; t++){
        const int p = t & 1;
        unsigned short* rh = Ahi(p);     unsigned short* rl = Alo(p);
        unsigned short* wh = Ahi(1 - p); unsigned short* wl = Alo(1 - p);

        f32x4 acc[3][4];
        #pragma unroll
        for (int mt = 0; mt < 3; mt++){
            #pragma unroll
            for (int j = 0; j < 4; j++){
                int s = 16*mt + 4*qq + j;
                float p0 = arena_f[6144 + s*64 + 32];
                float p1 = arena_f[6144 + s*64 + 33];
                #pragma unroll
                for (int nt = 0; nt < 4; nt++)
                    acc[mt][nt][j] = bias_d[nt] + wd0[nt]*p0 + wd1[nt]*p1;
            }
        }
        #pragma unroll
        for (int kt = 0; kt < 2; kt++){
            #pragma unroll
            for (int mt = 0; mt < 3; mt++){
                int idx = SWZ(16*mt + lo15, 32*kt + 8*qq);
                short8 ah = *reinterpret_cast<const short8*>(&rh[idx]);
                short8 al = *reinterpret_cast<const short8*>(&rl[idx]);
                #pragma unroll
                for (int nt = 0; nt < 4; nt++){
                    acc[mt][nt] = __builtin_amdgcn_mfma_f32_16x16x32_bf16(ah, dBh[nt][kt], acc[mt][nt], 0,0,0);
                    acc[mt][nt] = __builtin_amdgcn_mfma_f32_16x16x32_bf16(al, dBh[nt][kt], acc[mt][nt], 0,0,0);
                    acc[mt][nt] = __builtin_amdgcn_mfma_f32_16x16x32_bf16(ah, dBl[nt][kt], acc[mt][nt], 0,0,0);
                }
            }
        }
        nonlin_store(acc, wh, wl);   // writes buf[1-p] cols<64; p-slots untouched
        __syncthreads();             // h(t) visible for FC

        if (tid < 176){
            const int row = fbb*24 + fs;
            float part = 0.0f;
            #pragma unroll
            for (int e4 = 0; e4 < 4; e4++){
                int idx = SWZ(row, 32*fq + 8*e4);
                short8 hh = *reinterpret_cast<const short8*>(&wh[idx]);
                short8 ll = *reinterpret_cast<const short8*>(&wl[idx]);
                #pragma unroll
                for (int e = 0; e < 8; e++)
                    part = fmaf(bf_f((unsigned short)hh[e]) + bf_f((unsigned short)ll[e]),
                                fcw[8*e4 + e], part);
            }
            part += __shfl_xor(part, 1);
            if (fq == 0){
                float pred = part + fcb;
                float* outb = fbb ? outb1 : outb0;
                outb[(fs*PRED_LEN + t)*OUT_DIM + fo] = pred;
                arena_f[6144 + (fbb*24 + fs)*64 + 32 + fo] = pred;
            }
        }
        __syncthreads();             // p-slots ready for next step
    }
}

extern "C" void kernel_launch(void* const* d_in, const int* in_sizes, int n_in,
                              void* d_out, int out_size, void* d_ws, size_t ws_size,
                              hipStream_t stream) {
    const float* x        = (const float*)d_in[0];
    const float* enc_Wih  = (const float*)d_in[1];
    const float* enc_Whh  = (const float*)d_in[2];
    const float* enc_bih  = (const float*)d_in[3];
    const float* enc_bhh  = (const float*)d_in[4];
    const float* q_W      = (const float*)d_in[5];
    const float* q_b      = (const float*)d_in[6];
    const float* k_W      = (const float*)d_in[7];
    const float* k_b      = (const float*)d_in[8];
    const float* v_W      = (const float*)d_in[9];
    const float* v_b      = (const float*)d_in[10];
    const float* ln_g     = (const float*)d_in[11];
    const float* ln_b     = (const float*)d_in[12];
    const float* dec_Wih  = (const float*)d_in[13];
    const float* dec_Whh  = (const float*)d_in[14];
    const float* dec_bih  = (const float*)d_in[15];
    const float* dec_bhh  = (const float*)d_in[16];
    const float* fc_W     = (const float*)d_in[17];
    const float* fc_b     = (const float*)d_in[18];
    float* out = (float*)d_out;

    nfl_mfma<<<dim3(NB/2), dim3(256), 0, stream>>>(
        x, enc_Wih, enc_Whh, enc_bih, enc_bhh,
        q_W, q_b, k_W, k_b, v_W, v_b, ln_g, ln_b,
        dec_Wih, dec_Whh, dec_bih, dec_bhh, fc_W, fc_b, out);
}